// Round 1
// baseline (149.342 us; speedup 1.0000x reference)
//
#include <hip/hip_runtime.h>

#define WAVE 64

// ---------------------------------------------------------------------------
// Single fused kernel: one wave per segment.
//
// Segment bounds are found by per-wave binary search on the sorted batch
// array (lower_bound): even lanes search target=wid, odd lanes target=wid+1,
// so both bounds resolve in ONE dependent-load chain of ceil(log2 N) ~= 23
// steps. The top ~12 levels of the search tree touch only a few thousand
// distinct cache lines and are L1/L2-resident across the 16384 waves; the
// chain latency is hidden by 16 concurrent waves/SIMD. This removes the
// separate find_starts kernel: one fewer dispatch, no inter-kernel barrier,
// no dedicated 20 MB sequential batch pass, no workspace use (poison-immune
// by construction).
//
// Then: coalesced float4 accumulation (4x unrolled, 4 accumulators = 4 loads
// in flight), wave tree-reduction, lane 0 computes the fused MLP
// h=[u,mean] -> leaky_relu(h@W1+b1) -> @W2+b2.
// ---------------------------------------------------------------------------
__global__ void __launch_bounds__(256)
fused_seg_mean_mlp(const float4* __restrict__ x,
                   const int* __restrict__ batch,
                   const float* __restrict__ u,
                   const float* __restrict__ W1,   // [5,5] row-major
                   const float* __restrict__ b1,   // [5]
                   const float* __restrict__ W2,   // [5]
                   const float* __restrict__ b2,   // [1]
                   float* __restrict__ out,
                   int N, int B) {
    const int wid  = (blockIdx.x * blockDim.x + threadIdx.x) >> 6;
    const int lane = threadIdx.x & (WAVE - 1);
    if (wid >= B) return;

    // lower_bound(batch, t) = first i with batch[i] >= t.
    // Even lanes: t = wid (segment start). Odd lanes: t = wid+1 (segment end).
    // All lanes run the loop (no divergence in trip structure); only two
    // distinct addresses per wave per level -> 1-2 cache lines per step.
    const int t = wid + (lane & 1);
    int lo = 0, hi = N;
    while (lo < hi) {
        const int mid = (lo + hi) >> 1;           // N = 5e6, no overflow
        if (batch[mid] < t) lo = mid + 1;
        else                hi = mid;
    }
    const int start = __shfl(lo, 0);
    const int end   = __shfl(lo, 1);

    float4 a0 = make_float4(0.f, 0.f, 0.f, 0.f);
    float4 a1 = make_float4(0.f, 0.f, 0.f, 0.f);
    float4 a2 = make_float4(0.f, 0.f, 0.f, 0.f);
    float4 a3 = make_float4(0.f, 0.f, 0.f, 0.f);

    int i = start + lane;
    // Main loop: 4 independent loads in flight per lane.
    for (; i + 3 * WAVE < end; i += 4 * WAVE) {
        float4 v0 = x[i];
        float4 v1 = x[i + WAVE];
        float4 v2 = x[i + 2 * WAVE];
        float4 v3 = x[i + 3 * WAVE];
        a0.x += v0.x; a0.y += v0.y; a0.z += v0.z; a0.w += v0.w;
        a1.x += v1.x; a1.y += v1.y; a1.z += v1.z; a1.w += v1.w;
        a2.x += v2.x; a2.y += v2.y; a2.z += v2.z; a2.w += v2.w;
        a3.x += v3.x; a3.y += v3.y; a3.z += v3.z; a3.w += v3.w;
    }
    // Masked tail (up to 3 full wave-strides + one partial), per-lane exact.
    for (; i < end; i += WAVE) {
        float4 v = x[i];
        a0.x += v.x; a0.y += v.y; a0.z += v.z; a0.w += v.w;
    }

    a0.x += a1.x; a0.y += a1.y; a0.z += a1.z; a0.w += a1.w;
    a2.x += a3.x; a2.y += a3.y; a2.z += a3.z; a2.w += a3.w;
    a0.x += a2.x; a0.y += a2.y; a0.z += a2.z; a0.w += a2.w;

    #pragma unroll
    for (int off = 32; off > 0; off >>= 1) {
        a0.x += __shfl_down(a0.x, off);
        a0.y += __shfl_down(a0.y, off);
        a0.z += __shfl_down(a0.z, off);
        a0.w += __shfl_down(a0.w, off);
    }

    if (lane == 0) {
        const int cnt = end - start;
        const float inv = (cnt > 0) ? (1.0f / (float)cnt) : 0.0f;

        float h[5];
        h[0] = u[wid];
        h[1] = a0.x * inv;
        h[2] = a0.y * inv;
        h[3] = a0.z * inv;
        h[4] = a0.w * inv;

        float o = b2[0];
        #pragma unroll
        for (int j = 0; j < 5; ++j) {
            float s = b1[j];
            #pragma unroll
            for (int i2 = 0; i2 < 5; ++i2) s += h[i2] * W1[i2 * 5 + j];
            s = (s > 0.0f) ? s : 0.1f * s;   // leaky_relu, slope 0.1
            o += s * W2[j];
        }
        out[wid] = o;
    }
}

extern "C" void kernel_launch(void* const* d_in, const int* in_sizes, int n_in,
                              void* d_out, int out_size, void* d_ws, size_t ws_size,
                              hipStream_t stream) {
    const float* x     = (const float*)d_in[0];  // [N,4]
    const int*   batch = (const int*)  d_in[1];  // [N]
    const float* u     = (const float*)d_in[2];  // [B,1]
    const float* W1    = (const float*)d_in[3];  // [5,5]
    const float* b1    = (const float*)d_in[4];  // [5]
    const float* W2    = (const float*)d_in[5];  // [5,1]
    const float* b2    = (const float*)d_in[6];  // [1]
    float* out = (float*)d_out;

    const int N = in_sizes[0] / 4;
    const int B = out_size;                      // output is [B,1]

    (void)d_ws; (void)ws_size;                   // workspace unused (poison-immune)

    const int threads = 256;
    const int blocks  = (int)(((long long)B * WAVE + threads - 1) / threads);
    fused_seg_mean_mlp<<<blocks, threads, 0, stream>>>(
        (const float4*)x, batch, u, W1, b1, W2, b2, out, N, B);
}

// Round 3
// 141.049 us; speedup vs baseline: 1.0588x; 1.0588x over previous
//
#include <hip/hip_runtime.h>

#define WAVE 64

// clang vector types: __builtin_nontemporal_load requires a pointer to
// integer/float/pointer or a VECTOR of such (HIP_vector_type classes are
// rejected -> R2 compile failure).
typedef float v4f __attribute__((ext_vector_type(4)));
typedef int   v4i __attribute__((ext_vector_type(4)));

// ---------------------------------------------------------------------------
// Kernel A: segment start offsets from the sorted batch index, vectorized.
// seg_start[s] = min{ i : batch[i] >= s } for s in [0,B]; seg_start[B] = N.
// One int4 per thread; the quad's predecessor element comes from the
// neighbor lane via __shfl_up (only lane 0 of each wave loads it).
// Every s in [0,B] is written exactly once -> no init needed (poison-immune).
// Bandwidth-optimal (20 MB sequential, fully wave-parallel) — measured faster
// than a per-wave binary search fused into kernel B (R1: +4.8 us regression).
// ---------------------------------------------------------------------------
__global__ void find_starts4_kernel(const int* __restrict__ batch,
                                    int* __restrict__ seg_start,
                                    int N, int B) {
    const int tid  = blockIdx.x * blockDim.x + threadIdx.x;
    const int lane = threadIdx.x & (WAVE - 1);
    const long long i0 = (long long)tid * 4;
    const bool in   = (i0 < N);
    const bool full = (i0 + 3 < N);

    v4i q = (v4i)(0);
    if (full) q = __builtin_nontemporal_load(&((const v4i*)batch)[tid]);

    // Predecessor of this quad = last element of the previous thread's quad.
    // All threads participate in the shuffle before any early exit.
    int prevw = __shfl_up(q.w, 1);

    if (!in) return;

    int prev;
    if (lane == 0) prev = (i0 == 0) ? -1 : batch[i0 - 1];
    else           prev = prevw;      // predecessor quad is always full here

    if (full) {
        int e[4] = {q.x, q.y, q.z, q.w};
        #pragma unroll
        for (int k = 0; k < 4; ++k) {
            int cur = e[k];
            for (int s = prev + 1; s <= cur; ++s) seg_start[s] = (int)(i0 + k);
            prev = cur;
        }
    } else {
        for (long long j = i0; j < N; ++j) {
            int cur = batch[j];
            for (int s = prev + 1; s <= cur; ++s) seg_start[s] = (int)j;
            prev = cur;
        }
    }

    if (i0 + 4 >= N) {  // owner of the final quad writes the tail sentinels
        for (int s = prev + 1; s <= B; ++s) seg_start[s] = N;
    }
}

// ---------------------------------------------------------------------------
// Kernel B: one wave per segment. Coalesced float4 accumulation, 4x unrolled
// (4 non-temporal loads in flight), wave tree-reduction, then lane 0 computes
// the fused MLP: h=[u,mean] -> leaky_relu(h@W1+b1) -> @W2+b2.
// x is 80 MB streamed exactly once -> non-temporal to skip L2 pollution.
// ---------------------------------------------------------------------------
__global__ void __launch_bounds__(256)
seg_mean_mlp_kernel(const v4f* __restrict__ x,
                    const int* __restrict__ seg_start,
                    const float* __restrict__ u,
                    const float* __restrict__ W1,   // [5,5] row-major
                    const float* __restrict__ b1,   // [5]
                    const float* __restrict__ W2,   // [5]
                    const float* __restrict__ b2,   // [1]
                    float* __restrict__ out, int B) {
    const int wid  = (blockIdx.x * blockDim.x + threadIdx.x) >> 6;
    const int lane = threadIdx.x & (WAVE - 1);
    if (wid >= B) return;

    const int start = seg_start[wid];
    const int end   = seg_start[wid + 1];

    v4f a0 = (v4f)(0.f);
    v4f a1 = (v4f)(0.f);
    v4f a2 = (v4f)(0.f);
    v4f a3 = (v4f)(0.f);

    int i = start + lane;
    for (; i + 3 * WAVE < end; i += 4 * WAVE) {
        v4f v0 = __builtin_nontemporal_load(&x[i]);
        v4f v1 = __builtin_nontemporal_load(&x[i + WAVE]);
        v4f v2 = __builtin_nontemporal_load(&x[i + 2 * WAVE]);
        v4f v3 = __builtin_nontemporal_load(&x[i + 3 * WAVE]);
        a0 += v0; a1 += v1; a2 += v2; a3 += v3;
    }
    for (; i < end; i += WAVE) {
        v4f v = __builtin_nontemporal_load(&x[i]);
        a0 += v;
    }

    a0 += a1; a2 += a3; a0 += a2;

    float sx = a0.x, sy = a0.y, sz = a0.z, sw = a0.w;
    #pragma unroll
    for (int off = 32; off > 0; off >>= 1) {
        sx += __shfl_down(sx, off);
        sy += __shfl_down(sy, off);
        sz += __shfl_down(sz, off);
        sw += __shfl_down(sw, off);
    }

    if (lane == 0) {
        const int cnt = end - start;
        const float inv = (cnt > 0) ? (1.0f / (float)cnt) : 0.0f;

        float h[5];
        h[0] = u[wid];
        h[1] = sx * inv;
        h[2] = sy * inv;
        h[3] = sz * inv;
        h[4] = sw * inv;

        float o = b2[0];
        #pragma unroll
        for (int j = 0; j < 5; ++j) {
            float s = b1[j];
            #pragma unroll
            for (int i2 = 0; i2 < 5; ++i2) s += h[i2] * W1[i2 * 5 + j];
            s = (s > 0.0f) ? s : 0.1f * s;   // leaky_relu, slope 0.1
            o += s * W2[j];
        }
        out[wid] = o;
    }
}

extern "C" void kernel_launch(void* const* d_in, const int* in_sizes, int n_in,
                              void* d_out, int out_size, void* d_ws, size_t ws_size,
                              hipStream_t stream) {
    const float* x     = (const float*)d_in[0];  // [N,4]
    const int*   batch = (const int*)  d_in[1];  // [N]
    const float* u     = (const float*)d_in[2];  // [B,1]
    const float* W1    = (const float*)d_in[3];  // [5,5]
    const float* b1    = (const float*)d_in[4];  // [5]
    const float* W2    = (const float*)d_in[5];  // [5,1]
    const float* b2    = (const float*)d_in[6];  // [1]
    float* out = (float*)d_out;

    const int N = in_sizes[0] / 4;
    const int B = out_size;                      // output is [B,1]

    int* seg_start = (int*)d_ws;                 // [B+1] ints, fully rewritten

    const int quads = (N + 3) / 4;
    find_starts4_kernel<<<(quads + 255) / 256, 256, 0, stream>>>(batch, seg_start, N, B);

    const int threads = 256;
    const int blocks  = (int)(((long long)B * WAVE + threads - 1) / threads);
    seg_mean_mlp_kernel<<<blocks, threads, 0, stream>>>(
        (const v4f*)x, seg_start, u, W1, b1, W2, b2, out, B);
}